// Round 1
// baseline (175.486 us; speedup 1.0000x reference)
//
#include <hip/hip_runtime.h>

// relu(sum(relu(x))) over N=2^25 fp32 — R8: full-residency occupancy probe.
//
// Change vs R7 (175.3 us): force VGPR <= 64 via __launch_bounds__(256, 8) so
// all 2048 blocks (32 waves/CU) are co-resident, vs 16 waves/CU before.
// Same in-flight bytes per CU (256 KB), but 2x the independent load-return
// streams and zero mid-kernel block handoff. Implemented as a rolling 4+4
// double-buffer (8 loads in flight, 32 data VGPRs) instead of a 16-deep batch
// (64 data VGPRs). Summation tree is bit-identical to R7: chains s0..s3 still
// receive float4s v[0,4,8,12], v[1,5,9,13], ... in the same order.
//
// Evidence trail (rounds 1-7):
//  - nt > cached (176/181 vs 189/189): x is L3-cold at kernel time.
//  - blocked slabs > 8MB-strided streams (176 vs 181).
//  - same-address atomics cost ~100 us (R1).
//  - R7 claim "read path caps at 3.15 TB/s" is UNPROVEN: it halved the copy
//    number, but copy shares the bus both ways. Write-only fills hit 6.83 TB/s
//    (11 B/cyc/CU) on this machine; no read-only ceiling was ever demonstrated.
//    This round tests whether occupancy (16 waves/CU, ~84 VGPR) was the cap.

typedef float f32x4 __attribute__((ext_vector_type(4)));

#define NBLOCKS 2048
#define TPB     256
#define PER     16   // 2048 blocks * 256 thr * 16 = 2^23 float4 = 2^25 floats

__global__ __launch_bounds__(TPB, 8) void kan_partial(const f32x4* __restrict__ x4,
                                                      float* __restrict__ partials) {
    // Block-contiguous slab: block b covers [b*4096, (b+1)*4096) float4s.
    const f32x4* base = x4 + (size_t)blockIdx.x * (TPB * PER) + threadIdx.x;

    // Rolling double-buffer: groups g0..g3 of 4 float4 each; va/vb alternate.
    // 8 loads in flight at steady state, only 32 data VGPRs live.
    f32x4 va[4], vb[4];
    #pragma unroll
    for (int i = 0; i < 4; ++i)
        va[i] = __builtin_nontemporal_load(base + (0 * 4 + i) * TPB);   // g0
    #pragma unroll
    for (int i = 0; i < 4; ++i)
        vb[i] = __builtin_nontemporal_load(base + (1 * 4 + i) * TPB);   // g1

    float s0 = 0.0f, s1 = 0.0f, s2 = 0.0f, s3 = 0.0f;

    // Consume one group: arr[j] feeds chain sj. Chain contents across the
    // four groups match R7 exactly (s0: v0,v4,v8,v12; s1: v1,v5,v9,v13; ...).
#define CONSUME(arr) do {                                                                                  \
        s0 += fmaxf(arr[0].x, 0.0f) + fmaxf(arr[0].y, 0.0f) + fmaxf(arr[0].z, 0.0f) + fmaxf(arr[0].w, 0.0f); \
        s1 += fmaxf(arr[1].x, 0.0f) + fmaxf(arr[1].y, 0.0f) + fmaxf(arr[1].z, 0.0f) + fmaxf(arr[1].w, 0.0f); \
        s2 += fmaxf(arr[2].x, 0.0f) + fmaxf(arr[2].y, 0.0f) + fmaxf(arr[2].z, 0.0f) + fmaxf(arr[2].w, 0.0f); \
        s3 += fmaxf(arr[3].x, 0.0f) + fmaxf(arr[3].y, 0.0f) + fmaxf(arr[3].z, 0.0f) + fmaxf(arr[3].w, 0.0f); \
    } while (0)

    CONSUME(va);                                                        // consume g0
    #pragma unroll
    for (int i = 0; i < 4; ++i)
        va[i] = __builtin_nontemporal_load(base + (2 * 4 + i) * TPB);   // issue g2
    CONSUME(vb);                                                        // consume g1
    #pragma unroll
    for (int i = 0; i < 4; ++i)
        vb[i] = __builtin_nontemporal_load(base + (3 * 4 + i) * TPB);   // issue g3
    CONSUME(va);                                                        // consume g2
    CONSUME(vb);                                                        // consume g3
#undef CONSUME

    float s = (s0 + s1) + (s2 + s3);

    // wave-64 reduction
    #pragma unroll
    for (int off = 32; off > 0; off >>= 1)
        s += __shfl_down(s, off, 64);

    __shared__ float wsum[TPB / 64];
    const int lane = threadIdx.x & 63;
    const int wid  = threadIdx.x >> 6;
    if (lane == 0) wsum[wid] = s;
    __syncthreads();

    if (threadIdx.x == 0)
        partials[blockIdx.x] = wsum[0] + wsum[1] + wsum[2] + wsum[3];
}

__global__ __launch_bounds__(TPB) void kan_final(const float* __restrict__ partials,
                                                 float* __restrict__ out) {
    // 2048 partials, 256 threads -> 8 each; batch loads, then add.
    float p[NBLOCKS / TPB];
    #pragma unroll
    for (int i = 0; i < NBLOCKS / TPB; ++i)
        p[i] = partials[threadIdx.x + i * TPB];

    float s = 0.0f;
    #pragma unroll
    for (int i = 0; i < NBLOCKS / TPB; ++i)
        s += p[i];

    #pragma unroll
    for (int off = 32; off > 0; off >>= 1)
        s += __shfl_down(s, off, 64);

    __shared__ float wsum[TPB / 64];
    const int lane = threadIdx.x & 63;
    const int wid  = threadIdx.x >> 6;
    if (lane == 0) wsum[wid] = s;
    __syncthreads();

    if (threadIdx.x == 0) {
        float total = wsum[0] + wsum[1] + wsum[2] + wsum[3];
        out[0] = fmaxf(total, 0.0f);
    }
}

extern "C" void kernel_launch(void* const* d_in, const int* in_sizes, int n_in,
                              void* d_out, int out_size, void* d_ws, size_t ws_size,
                              hipStream_t stream) {
    const f32x4* x4 = (const f32x4*)d_in[0];
    float* out = (float*)d_out;
    float* partials = (float*)d_ws;  // 2048 floats, all written by kan_partial

    kan_partial<<<NBLOCKS, TPB, 0, stream>>>(x4, partials);
    kan_final<<<1, TPB, 0, stream>>>(partials, out);
}